// Round 3
// baseline (770.668 us; speedup 1.0000x reference)
//
#include <hip/hip_runtime.h>
#include <hip/hip_bf16.h>
#include <stdint.h>

// MaskedDeepDAN on MI355X (gfx950). B=8192, D_IN=2048, H=1024, C=1000.
// R2 strategy: remove all layout/dtype guessing.
//  - inputs resolved by SIZE SIGNATURE (works for dict-insertion / sorted-key
//    x flat-37 / stacked-13 layouts: within each equal-size class the relative
//    order is identical across all four).
//  - float dtype (fp32 vs bf16) and mask dtype (i32/u8/bf16/f32) detected ON
//    DEVICE from bit statistics; all compute uses converted bf16 ws buffers.
//  - final store width follows detected float dtype.
// GEMM: m97-style 128x128 tile, 4 waves, 16x16x32 bf16 MFMA, BK=32,
// global_load_lds width=16, A [M,K] row-major, B [N,K] row-major.

typedef unsigned short ushort_t;
typedef __bf16 bf16x8 __attribute__((ext_vector_type(8)));
typedef float f32x4 __attribute__((ext_vector_type(4)));

__device__ __forceinline__ void gl_lds16(const void* g, void* l) {
  typedef __attribute__((address_space(1))) void gvoid;
  typedef __attribute__((address_space(3))) void lvoid;
  __builtin_amdgcn_global_load_lds((gvoid*)(void*)g, (lvoid*)l, 16, 0, 0);
}

__device__ __forceinline__ ushort_t f2b(float f) {
  __hip_bfloat16 h = (__hip_bfloat16)f;
  return *(ushort_t*)&h;
}

// ---------------- dtype detection ----------------
// flags[0] = 1 if floats are fp32, 0 if bf16
// flags[1] = mask mode: 0=int32, 1=uint8, 2=bf16(u16), 3=fp32
__global__ void detect_kernel(const ushort_t* x, const ushort_t* mf, int* flags) {
  __shared__ int s[4];
  if (threadIdx.x < 4) s[threadIdx.x] = 0;
  __syncthreads();
  int expout = 0, m3f80_even = 0, m3f80_odd = 0, mhi01 = 0;
  for (int k = threadIdx.x; k < 2048; k += 256) {
    ushort_t w = x[k];
    int e = (w >> 7) & 0xFF;
    if (e < 96 || e > 144) expout++;           // bf16 N(0,1): always in range
    ushort_t mw = mf[k];
    if (mw == 0x3F80) { if (k & 1) m3f80_odd++; else m3f80_even++; }
    if ((mw >> 8) == 1) mhi01++;               // uint8 mask pairs
  }
  atomicAdd(&s[0], expout);
  atomicAdd(&s[1], m3f80_even);
  atomicAdd(&s[2], m3f80_odd);
  atomicAdd(&s[3], mhi01);
  __syncthreads();
  if (threadIdx.x == 0) {
    flags[0] = (s[0] > 100) ? 1 : 0;
    int mmode = 0;
    if (s[1] > 100) mmode = 2;                 // bf16 1.0 at even (lo) positions
    else if (s[2] > 100) mmode = 3;            // fp32 1.0 (hi half only)
    else if (s[3] > 200) mmode = 1;            // uint8
    flags[1] = mmode;
  }
}

// ---------------- x conversion (always into ws as bf16) ----------------
__global__ void convert_x(const void* x, ushort_t* out, const int* flags, int n) {
  const bool f32 = flags[0] != 0;
  int i = (blockIdx.x * blockDim.x + threadIdx.x) * 8;
  if (i >= n) return;
  ushort_t o[8];
  if (f32) {
    const float4* p = (const float4*)((const float*)x + i);
    float4 a = p[0], b = p[1];
    o[0] = f2b(a.x); o[1] = f2b(a.y); o[2] = f2b(a.z); o[3] = f2b(a.w);
    o[4] = f2b(b.x); o[5] = f2b(b.y); o[6] = f2b(b.z); o[7] = f2b(b.w);
    *(uint4*)(out + i) = *(uint4*)o;
  } else {
    *(uint4*)(out + i) = *(const uint4*)((const ushort_t*)x + i);
  }
}

// ---------------- weight/bias masking + conversion ----------------
struct PrepEnt {
  const void* w; size_t woff;   // element offsets (dtype-width applied on device)
  const void* m; size_t moff;   // m == nullptr -> no mask (bias)
  ushort_t* o;
  int n;
  int valid;                    // i >= valid -> write 0 (padding)
};
struct PrepAll { PrepEnt e[24]; };

__global__ void prep_weights(PrepAll p, const int* flags) {
  const bool f32 = flags[0] != 0;
  const int mmode = flags[1];
  const PrepEnt ent = p.e[blockIdx.y];
  const int stride = blockDim.x * gridDim.x;
  for (int i = blockIdx.x * blockDim.x + threadIdx.x; i < ent.n; i += stride) {
    ushort_t v = 0;
    if (i < ent.valid) {
      bool mk = true;
      if (ent.m) {
        if (mmode == 0)      mk = ((const int*)ent.m + ent.moff)[i] != 0;
        else if (mmode == 1) mk = ((const unsigned char*)ent.m + ent.moff)[i] != 0;
        else if (mmode == 2) mk = ((const ushort_t*)ent.m + ent.moff)[i] != 0;
        else                 mk = ((const unsigned int*)ent.m + ent.moff)[i] != 0;
      }
      if (mk) {
        if (f32) v = f2b(((const float*)ent.w + ent.woff)[i]);
        else     v = ((const ushort_t*)ent.w + ent.woff)[i];
      }
    }
    ent.o[i] = v;
  }
}

// ---------------- GEMM: C[M,N] = A[M,K] * B[N,K]^T + bias ----------------
// grid = (N_pad/128, M/128), block = 256. A,B,bias are bf16 (ws). C is bf16
// unless of32flag says fp32 (final layer only).
template <bool RELU, bool ACCUM, bool NGUARD>
__launch_bounds__(256)
__global__ void gemm_bt(const __hip_bfloat16* __restrict__ A,
                        const __hip_bfloat16* __restrict__ Bw,
                        const __hip_bfloat16* __restrict__ bias,
                        void* Cv, const int* of32flag,
                        int K, int N_real, int ldc)
{
  __shared__ __align__(16) ushort_t As[128 * 32];
  __shared__ __align__(16) ushort_t Bs[128 * 32];

  const bool of32 = (of32flag != nullptr) && (of32flag[0] != 0);
  __hip_bfloat16* C = (__hip_bfloat16*)Cv;
  float* Cf = (float*)Cv;

  const int tid  = threadIdx.x;
  const int lane = tid & 63;
  const int wave = tid >> 6;
  const int wm = (wave >> 1) * 64;
  const int wn = (wave & 1) * 64;
  const int fr = lane & 15;
  const int kg = lane >> 4;
  const int bm = blockIdx.y * 128;
  const int bn = blockIdx.x * 128;

  const int srow = tid >> 2;
  const int scol = (tid & 3) * 8;
  const ushort_t* ga0 = (const ushort_t*)A + (size_t)(bm + srow) * K + scol;
  const ushort_t* ga1 = ga0 + (size_t)64 * K;
  const ushort_t* gb0 = (const ushort_t*)Bw + (size_t)(bn + srow) * K + scol;
  const ushort_t* gb1 = gb0 + (size_t)64 * K;
  ushort_t* lA0 = As + wave * 512;
  ushort_t* lA1 = lA0 + 2048;
  ushort_t* lB0 = Bs + wave * 512;
  ushort_t* lB1 = lB0 + 2048;

  f32x4 acc[4][4];
#pragma unroll
  for (int i = 0; i < 4; i++)
#pragma unroll
    for (int j = 0; j < 4; j++) acc[i][j] = (f32x4){0.f, 0.f, 0.f, 0.f};

  const bf16x8* Asv = (const bf16x8*)As;
  const bf16x8* Bsv = (const bf16x8*)Bs;

  for (int k0 = 0; k0 < K; k0 += 32) {
    __syncthreads();
    gl_lds16(ga0, lA0);
    gl_lds16(ga1, lA1);
    gl_lds16(gb0, lB0);
    gl_lds16(gb1, lB1);
    ga0 += 32; ga1 += 32; gb0 += 32; gb1 += 32;
    __syncthreads();

    bf16x8 af[4], bfr[4];
#pragma unroll
    for (int i = 0; i < 4; i++) af[i]  = Asv[(wm + i * 16 + fr) * 4 + kg];
#pragma unroll
    for (int i = 0; i < 4; i++) bfr[i] = Bsv[(wn + i * 16 + fr) * 4 + kg];
#pragma unroll
    for (int mi = 0; mi < 4; mi++)
#pragma unroll
      for (int ni = 0; ni < 4; ni++)
        acc[mi][ni] = __builtin_amdgcn_mfma_f32_16x16x32_bf16(
            af[mi], bfr[ni], acc[mi][ni], 0, 0, 0);
  }

  // C/D layout: col = lane&15, row = (lane>>4)*4 + reg
#pragma unroll
  for (int ni = 0; ni < 4; ni++) {
    const int c = bn + wn + ni * 16 + fr;
    if (NGUARD && c >= N_real) continue;
    const float bb = (float)bias[c];
#pragma unroll
    for (int mi = 0; mi < 4; mi++) {
      const int r0 = bm + wm + mi * 16 + kg * 4;
#pragma unroll
      for (int j = 0; j < 4; j++) {
        const size_t idx = (size_t)(r0 + j) * ldc + c;
        float o = acc[mi][ni][j] + bb;
        if (RELU) o = fmaxf(o, 0.0f);
        if (ACCUM) o += (float)C[idx];
        if (of32) Cf[idx] = o;
        else      C[idx] = (__hip_bfloat16)o;
      }
    }
  }
}

extern "C" void kernel_launch(void* const* d_in, const int* in_sizes, int n_in,
                              void* d_out, int out_size, void* d_ws, size_t ws_size,
                              hipStream_t stream) {
  (void)out_size; (void)ws_size;
  const int Bm = 8192, DIN = 2048, H = 1024, Cn = 1000;
  const size_t HH = (size_t)H * H;

  // ---- size-signature input resolver ----
  struct PO { const void* p; size_t off; };
  PO x{d_in[0], 0}, Wf{d_in[0], 0}, mf{d_in[0], 0}, Wo{d_in[0], 0}, mo{d_in[0], 0};
  PO bf{d_in[0], 0}, bo{d_in[0], 0};
  PO mW[4], mM[4], mB[4], sW[6], sM[6], sB[6];
  for (int i = 0; i < 4; i++) { mW[i] = {d_in[0], 0}; mM[i] = mW[i]; mB[i] = mW[i]; }
  for (int i = 0; i < 6; i++) { sW[i] = {d_in[0], 0}; sM[i] = sW[i]; sB[i] = sW[i]; }

  int c2M = 0, c1M = 0, c1k = 0, cWoMo = 0;
  for (int i = 0; i < n_in; i++) {
    const int s = in_sizes[i];
    const void* p = d_in[i];
    switch (s) {
      case 16777216: x = {p, 0}; break;                       // x [8192,2048]
      case 2097152:  if (c2M++ == 0) Wf = {p, 0}; else mf = {p, 0}; break;
      case 1048576: {                                         // H*H, flat: 20x
        int j = c1M++;
        if (j < 4)       mW[j]      = {p, 0};
        else if (j < 8)  mM[j - 4]  = {p, 0};
        else if (j < 14) sW[j - 8]  = {p, 0};
        else if (j < 20) sM[j - 14] = {p, 0};
        break;
      }
      case 1024: {                                            // biases, flat: 11x
        int j = c1k++;
        if (j == 0)      bf         = {p, 0};
        else if (j < 5)  mB[j - 1]  = {p, 0};
        else if (j < 11) sB[j - 5]  = {p, 0};
        break;
      }
      case 1024000: if (cWoMo++ == 0) Wo = {p, 0}; else mo = {p, 0}; break;
      case 1000: bo = {p, 0}; break;
      // stacked-list variants (W before m in both insertion & sorted order):
      case 4194304: {                                         // main_W / main_m [4,H,H]
        static thread_local int c4 = 0; // not used; avoid UB — replaced below
        break;
      }
      default: break;
    }
  }
  // second pass for stacked sizes (can't use static counters above)
  {
    int c4 = 0, c6 = 0;
    for (int i = 0; i < n_in; i++) {
      const int s = in_sizes[i];
      const void* p = d_in[i];
      if (s == 4194304) {            // [4,H,H]: first=main_W, second=main_m
        for (int t = 0; t < 4; t++) {
          if (c4 == 0) mW[t] = {p, t * HH}; else mM[t] = {p, t * HH};
        }
        c4++;
      } else if (s == 6291456) {     // [6,H,H]: first=skip_W, second=skip_m
        for (int t = 0; t < 6; t++) {
          if (c6 == 0) sW[t] = {p, t * HH}; else sM[t] = {p, t * HH};
        }
        c6++;
      } else if (s == 4096) {        // [4,H] main_b
        for (int t = 0; t < 4; t++) mB[t] = {p, (size_t)t * H};
      } else if (s == 6144) {        // [6,H] skip_b
        for (int t = 0; t < 6; t++) sB[t] = {p, (size_t)t * H};
      }
    }
  }

  // ---- workspace layout (ushort units) ----
  ushort_t* wsp = (ushort_t*)d_ws;
  size_t off = 0;
  int* flags = (int*)wsp; off += 32;                      // flags[0..1]
  ushort_t* xc = wsp + off; off += (size_t)Bm * DIN;      // converted x
  __hip_bfloat16* r[5];
  for (int i = 0; i < 5; i++) { r[i] = (__hip_bfloat16*)(wsp + off); off += (size_t)Bm * H; }
  ushort_t* wWf = wsp + off; off += (size_t)H * DIN;
  ushort_t* wMain[4];
  for (int i = 0; i < 4; i++) { wMain[i] = wsp + off; off += HH; }
  ushort_t* wSkip[6];
  for (int k = 0; k < 6; k++) { wSkip[k] = wsp + off; off += HH; }
  ushort_t* wWo = wsp + off; off += (size_t)1024 * 1024;  // padded to 1024 rows
  ushort_t* cbf_ = wsp + off; off += 1024;
  ushort_t* cmB[4];
  for (int i = 0; i < 4; i++) { cmB[i] = wsp + off; off += 1024; }
  ushort_t* csB[6];
  for (int k = 0; k < 6; k++) { csB[k] = wsp + off; off += 1024; }
  ushort_t* cbo = wsp + off; off += 1024;

  // ---- launches ----
  detect_kernel<<<1, 256, 0, stream>>>((const ushort_t*)x.p, (const ushort_t*)mf.p, flags);
  convert_x<<<(Bm * DIN) / (8 * 256), 256, 0, stream>>>(x.p, xc, flags, Bm * DIN);

  PrepAll p;
  p.e[0]  = { Wf.p, Wf.off, mf.p, mf.off, wWf, H * DIN, H * DIN };
  for (int i = 0; i < 4; i++)
    p.e[1 + i] = { mW[i].p, mW[i].off, mM[i].p, mM[i].off, wMain[i], (int)HH, (int)HH };
  for (int k = 0; k < 6; k++)
    p.e[5 + k] = { sW[k].p, sW[k].off, sM[k].p, sM[k].off, wSkip[k], (int)HH, (int)HH };
  p.e[11] = { Wo.p, Wo.off, mo.p, mo.off, wWo, 1024 * 1024, Cn * H };
  p.e[12] = { bf.p, bf.off, nullptr, 0, cbf_, H, H };
  for (int i = 0; i < 4; i++)
    p.e[13 + i] = { mB[i].p, mB[i].off, nullptr, 0, cmB[i], H, H };
  for (int k = 0; k < 6; k++)
    p.e[17 + k] = { sB[k].p, sB[k].off, nullptr, 0, csB[k], H, H };
  p.e[23] = { bo.p, bo.off, nullptr, 0, cbo, Cn, Cn };
  prep_weights<<<dim3(128, 24), dim3(256), 0, stream>>>(p, flags);

  typedef const __hip_bfloat16* cb;
  const dim3 g(8, 64), b(256);

  gemm_bt<true, false, false><<<g, b, 0, stream>>>(
      (cb)xc, (cb)wWf, (cb)cbf_, r[0], nullptr, DIN, H, H);
  gemm_bt<true, false, false><<<g, b, 0, stream>>>(
      r[0], (cb)wMain[0], (cb)cmB[0], r[1], nullptr, H, H, H);
  gemm_bt<true, false, false><<<g, b, 0, stream>>>(
      r[1], (cb)wMain[1], (cb)cmB[1], r[2], nullptr, H, H, H);
  gemm_bt<true, true, false><<<g, b, 0, stream>>>(
      r[0], (cb)wSkip[0], (cb)csB[0], r[2], nullptr, H, H, H);
  gemm_bt<true, false, false><<<g, b, 0, stream>>>(
      r[2], (cb)wMain[2], (cb)cmB[2], r[3], nullptr, H, H, H);
  gemm_bt<true, true, false><<<g, b, 0, stream>>>(
      r[0], (cb)wSkip[1], (cb)csB[1], r[3], nullptr, H, H, H);
  gemm_bt<true, true, false><<<g, b, 0, stream>>>(
      r[1], (cb)wSkip[2], (cb)csB[2], r[3], nullptr, H, H, H);
  gemm_bt<true, false, false><<<g, b, 0, stream>>>(
      r[3], (cb)wMain[3], (cb)cmB[3], r[4], nullptr, H, H, H);
  gemm_bt<true, true, false><<<g, b, 0, stream>>>(
      r[0], (cb)wSkip[3], (cb)csB[3], r[4], nullptr, H, H, H);
  gemm_bt<true, true, false><<<g, b, 0, stream>>>(
      r[1], (cb)wSkip[4], (cb)csB[4], r[4], nullptr, H, H, H);
  gemm_bt<true, true, false><<<g, b, 0, stream>>>(
      r[2], (cb)wSkip[5], (cb)csB[5], r[4], nullptr, H, H, H);
  gemm_bt<false, false, true><<<g, b, 0, stream>>>(
      r[4], (cb)wWo, (cb)cbo, d_out, flags, H, Cn, Cn);
}

// Round 4
// 664.682 us; speedup vs baseline: 1.1595x; 1.1595x over previous
//
#include <hip/hip_runtime.h>
#include <hip/hip_bf16.h>
#include <stdint.h>

// MaskedDeepDAN on MI355X (gfx950). B=8192, D_IN=2048, H=1024, C=1000.
// R3: (1) per-layer fused multi-source GEMM — each hidden layer's main+skip
// branches computed in ONE kernel, per-branch bias+relu folded in registers
// (fp32), single bf16 store; kills 6 bf16 RMW accumulate GEMMs and halves
// launch count. (2) vectorized prep_weights (8 elts/thread, uint4/float4).
// Input resolution by size signature + on-device dtype detection (R2, verified).
// GEMM core: m97 structure — 128x128 tile, 4 waves, 16x16x32 bf16 MFMA, BK=32,
// global_load_lds width=16, A [M,K] row-major, B [N,K] row-major.

typedef unsigned short ushort_t;
typedef __bf16 bf16x8 __attribute__((ext_vector_type(8)));
typedef float f32x4 __attribute__((ext_vector_type(4)));

__device__ __forceinline__ void gl_lds16(const void* g, void* l) {
  typedef __attribute__((address_space(1))) void gvoid;
  typedef __attribute__((address_space(3))) void lvoid;
  __builtin_amdgcn_global_load_lds((gvoid*)(void*)g, (lvoid*)l, 16, 0, 0);
}

__device__ __forceinline__ ushort_t f2b(float f) {
  __hip_bfloat16 h = (__hip_bfloat16)f;
  return *(ushort_t*)&h;
}

// ---------------- dtype detection (verified R2) ----------------
// flags[0] = 1 if floats are fp32, 0 if bf16
// flags[1] = mask mode: 0=int32, 1=uint8, 2=bf16(u16), 3=fp32
__global__ void detect_kernel(const ushort_t* x, const ushort_t* mf, int* flags) {
  __shared__ int s[4];
  if (threadIdx.x < 4) s[threadIdx.x] = 0;
  __syncthreads();
  int expout = 0, m3f80_even = 0, m3f80_odd = 0, mhi01 = 0;
  for (int k = threadIdx.x; k < 2048; k += 256) {
    ushort_t w = x[k];
    int e = (w >> 7) & 0xFF;
    if (e < 96 || e > 144) expout++;
    ushort_t mw = mf[k];
    if (mw == 0x3F80) { if (k & 1) m3f80_odd++; else m3f80_even++; }
    if ((mw >> 8) == 1) mhi01++;
  }
  atomicAdd(&s[0], expout);
  atomicAdd(&s[1], m3f80_even);
  atomicAdd(&s[2], m3f80_odd);
  atomicAdd(&s[3], mhi01);
  __syncthreads();
  if (threadIdx.x == 0) {
    flags[0] = (s[0] > 100) ? 1 : 0;
    int mmode = 0;
    if (s[1] > 100) mmode = 2;
    else if (s[2] > 100) mmode = 3;
    else if (s[3] > 200) mmode = 1;
    flags[1] = mmode;
  }
}

// ---------------- x conversion (into ws as bf16) ----------------
__global__ void convert_x(const void* x, ushort_t* out, const int* flags, int n) {
  const bool f32 = flags[0] != 0;
  int i = (blockIdx.x * blockDim.x + threadIdx.x) * 8;
  if (i >= n) return;
  if (f32) {
    const float4* p = (const float4*)((const float*)x + i);
    float4 a = p[0], b = p[1];
    ushort_t o[8];
    o[0] = f2b(a.x); o[1] = f2b(a.y); o[2] = f2b(a.z); o[3] = f2b(a.w);
    o[4] = f2b(b.x); o[5] = f2b(b.y); o[6] = f2b(b.z); o[7] = f2b(b.w);
    *(uint4*)(out + i) = *(uint4*)o;
  } else {
    *(uint4*)(out + i) = *(const uint4*)((const ushort_t*)x + i);
  }
}

// ---------------- weight/bias masking + conversion (vectorized) ----------------
// All entry sizes and valid boundaries are multiples of 8, so chunks never
// straddle the valid boundary.
struct PrepEnt {
  const void* w; size_t woff;   // element offsets
  const void* m; size_t moff;   // nullptr -> no mask (bias)
  ushort_t* o;
  int n;                        // multiple of 8
  int valid;                    // multiple of 8; i >= valid -> 0
};
struct PrepAll { PrepEnt e[24]; };

__global__ void prep_weights(PrepAll p, const int* flags) {
  const bool f32 = flags[0] != 0;
  const int mmode = flags[1];
  const PrepEnt e = p.e[blockIdx.y];
  const int nch = e.n >> 3;
  const int stride = blockDim.x * gridDim.x;
  for (int ci = blockIdx.x * blockDim.x + threadIdx.x; ci < nch; ci += stride) {
    const int i = ci << 3;
    ushort_t o[8] = {0, 0, 0, 0, 0, 0, 0, 0};
    if (i < e.valid) {
      ushort_t wb[8];
      if (f32) {
        const float* wp = (const float*)e.w + e.woff + i;
        float4 a = *(const float4*)wp;
        float4 b = *(const float4*)(wp + 4);
        wb[0] = f2b(a.x); wb[1] = f2b(a.y); wb[2] = f2b(a.z); wb[3] = f2b(a.w);
        wb[4] = f2b(b.x); wb[5] = f2b(b.y); wb[6] = f2b(b.z); wb[7] = f2b(b.w);
      } else {
        *(uint4*)wb = *(const uint4*)((const ushort_t*)e.w + e.woff + i);
      }
      unsigned mk = 0xFF;
      if (e.m) {
        mk = 0;
        if (mmode == 0) {
          const int4* mp = (const int4*)((const int*)e.m + e.moff + i);
          int4 a = mp[0], b = mp[1];
          mk = (a.x != 0) | ((a.y != 0) << 1) | ((a.z != 0) << 2) | ((a.w != 0) << 3) |
               ((b.x != 0) << 4) | ((b.y != 0) << 5) | ((b.z != 0) << 6) | ((b.w != 0) << 7);
        } else if (mmode == 1) {
          const uint2 mv = *(const uint2*)((const unsigned char*)e.m + e.moff + i);
          const unsigned char* mb = (const unsigned char*)&mv;
          for (int j = 0; j < 8; j++) mk |= (mb[j] != 0) << j;
        } else if (mmode == 2) {
          uint4 mv = *(const uint4*)((const ushort_t*)e.m + e.moff + i);
          const ushort_t* ms = (const ushort_t*)&mv;
          for (int j = 0; j < 8; j++) mk |= (ms[j] != 0) << j;
        } else {
          const uint4* mp = (const uint4*)((const unsigned int*)e.m + e.moff + i);
          uint4 a = mp[0], b = mp[1];
          const unsigned* u = (const unsigned*)&a;
          const unsigned* v = (const unsigned*)&b;
          for (int j = 0; j < 4; j++) mk |= (u[j] != 0) << j;
          for (int j = 0; j < 4; j++) mk |= (v[j] != 0) << (4 + j);
        }
      }
#pragma unroll
      for (int j = 0; j < 8; j++) o[j] = ((mk >> j) & 1) ? wb[j] : (ushort_t)0;
    }
    *(uint4*)(e.o + i) = *(uint4*)o;
  }
}

// ---------------- fused multi-source GEMM ----------------
// C[M,N] = sum_s relu(A_s[M,K] * B_s[N,K]^T + bias_s)   (RELU per branch)
// grid = (N_pad/128, M/128), block = 256.
struct GemmSrc { const ushort_t* A; const ushort_t* B; const ushort_t* bias; };
struct GemmArgs { GemmSrc s[4]; };

template <int NSRC, bool RELU, bool NGUARD>
__launch_bounds__(256)
__global__ void gemm_multi(GemmArgs args, void* Cv, const int* of32flag,
                           int K, int N_real, int ldc)
{
  __shared__ __align__(16) ushort_t As[128 * 32];
  __shared__ __align__(16) ushort_t Bs[128 * 32];

  const bool of32 = (of32flag != nullptr) && (of32flag[0] != 0);
  __hip_bfloat16* C = (__hip_bfloat16*)Cv;
  float* Cf = (float*)Cv;

  const int tid  = threadIdx.x;
  const int lane = tid & 63;
  const int wave = tid >> 6;
  const int wm = (wave >> 1) * 64;
  const int wn = (wave & 1) * 64;
  const int fr = lane & 15;
  const int kg = lane >> 4;
  const int bm = blockIdx.y * 128;
  const int bn = blockIdx.x * 128;

  const int srow = tid >> 2;
  const int scol = (tid & 3) * 8;
  ushort_t* lA0 = As + wave * 512;
  ushort_t* lA1 = lA0 + 2048;
  ushort_t* lB0 = Bs + wave * 512;
  ushort_t* lB1 = lB0 + 2048;

  const bf16x8* Asv = (const bf16x8*)As;
  const bf16x8* Bsv = (const bf16x8*)Bs;

  f32x4 out_acc[4][4];
#pragma unroll
  for (int i = 0; i < 4; i++)
#pragma unroll
    for (int j = 0; j < 4; j++) out_acc[i][j] = (f32x4){0.f, 0.f, 0.f, 0.f};

  for (int s = 0; s < NSRC; s++) {
    const ushort_t* ga0 = args.s[s].A + (size_t)(bm + srow) * K + scol;
    const ushort_t* ga1 = ga0 + (size_t)64 * K;
    const ushort_t* gb0 = args.s[s].B + (size_t)(bn + srow) * K + scol;
    const ushort_t* gb1 = gb0 + (size_t)64 * K;

    f32x4 acc[4][4];
#pragma unroll
    for (int i = 0; i < 4; i++)
#pragma unroll
      for (int j = 0; j < 4; j++) acc[i][j] = (f32x4){0.f, 0.f, 0.f, 0.f};

    for (int k0 = 0; k0 < K; k0 += 32) {
      __syncthreads();                 // prior ds_reads done
      gl_lds16(ga0, lA0);
      gl_lds16(ga1, lA1);
      gl_lds16(gb0, lB0);
      gl_lds16(gb1, lB1);
      ga0 += 32; ga1 += 32; gb0 += 32; gb1 += 32;
      __syncthreads();                 // staging complete

      bf16x8 af[4], bfr[4];
#pragma unroll
      for (int i = 0; i < 4; i++) af[i]  = Asv[(wm + i * 16 + fr) * 4 + kg];
#pragma unroll
      for (int i = 0; i < 4; i++) bfr[i] = Bsv[(wn + i * 16 + fr) * 4 + kg];
#pragma unroll
      for (int mi = 0; mi < 4; mi++)
#pragma unroll
        for (int ni = 0; ni < 4; ni++)
          acc[mi][ni] = __builtin_amdgcn_mfma_f32_16x16x32_bf16(
              af[mi], bfr[ni], acc[mi][ni], 0, 0, 0);
    }

    // per-branch epilogue: bias + relu, accumulate fp32
    const ushort_t* bias = args.s[s].bias;
#pragma unroll
    for (int ni = 0; ni < 4; ni++) {
      const int c = bn + wn + ni * 16 + fr;
      if (NGUARD && c >= N_real) continue;
      const float bb = (float)*(const __hip_bfloat16*)(bias + c);
#pragma unroll
      for (int mi = 0; mi < 4; mi++)
#pragma unroll
        for (int j = 0; j < 4; j++) {
          float v = acc[mi][ni][j] + bb;
          if (RELU) v = fmaxf(v, 0.0f);
          out_acc[mi][ni][j] += v;
        }
    }
  }

  // store: C/D layout col = lane&15, row = (lane>>4)*4 + reg
#pragma unroll
  for (int ni = 0; ni < 4; ni++) {
    const int c = bn + wn + ni * 16 + fr;
    if (NGUARD && c >= N_real) continue;
#pragma unroll
    for (int mi = 0; mi < 4; mi++) {
      const int r0 = bm + wm + mi * 16 + kg * 4;
#pragma unroll
      for (int j = 0; j < 4; j++) {
        const size_t idx = (size_t)(r0 + j) * ldc + c;
        if (of32) Cf[idx] = out_acc[mi][ni][j];
        else      C[idx]  = (__hip_bfloat16)out_acc[mi][ni][j];
      }
    }
  }
}

extern "C" void kernel_launch(void* const* d_in, const int* in_sizes, int n_in,
                              void* d_out, int out_size, void* d_ws, size_t ws_size,
                              hipStream_t stream) {
  (void)out_size; (void)ws_size;
  const int Bm = 8192, DIN = 2048, H = 1024, Cn = 1000;
  const size_t HH = (size_t)H * H;

  // ---- size-signature input resolver (verified R2) ----
  struct PO { const void* p; size_t off; };
  PO x{d_in[0], 0}, Wf{d_in[0], 0}, mf{d_in[0], 0}, Wo{d_in[0], 0}, mo{d_in[0], 0};
  PO bf{d_in[0], 0}, bo{d_in[0], 0};
  PO mW[4], mM[4], mB[4], sW[6], sM[6], sB[6];
  for (int i = 0; i < 4; i++) { mW[i] = {d_in[0], 0}; mM[i] = mW[i]; mB[i] = mW[i]; }
  for (int i = 0; i < 6; i++) { sW[i] = {d_in[0], 0}; sM[i] = sW[i]; sB[i] = sW[i]; }

  {
    int c2M = 0, c1M = 0, c1k = 0, cWoMo = 0, c4 = 0, c6 = 0;
    for (int i = 0; i < n_in; i++) {
      const int s = in_sizes[i];
      const void* p = d_in[i];
      switch (s) {
        case 16777216: x = {p, 0}; break;
        case 2097152:  if (c2M++ == 0) Wf = {p, 0}; else mf = {p, 0}; break;
        case 1048576: {
          int j = c1M++;
          if (j < 4)       mW[j]      = {p, 0};
          else if (j < 8)  mM[j - 4]  = {p, 0};
          else if (j < 14) sW[j - 8]  = {p, 0};
          else if (j < 20) sM[j - 14] = {p, 0};
          break;
        }
        case 1024: {
          int j = c1k++;
          if (j == 0)      bf        = {p, 0};
          else if (j < 5)  mB[j - 1] = {p, 0};
          else if (j < 11) sB[j - 5] = {p, 0};
          break;
        }
        case 1024000: if (cWoMo++ == 0) Wo = {p, 0}; else mo = {p, 0}; break;
        case 1000: bo = {p, 0}; break;
        case 4194304:
          for (int t = 0; t < 4; t++) {
            if (c4 == 0) mW[t] = {p, t * HH}; else mM[t] = {p, t * HH};
          }
          c4++; break;
        case 6291456:
          for (int t = 0; t < 6; t++) {
            if (c6 == 0) sW[t] = {p, t * HH}; else sM[t] = {p, t * HH};
          }
          c6++; break;
        case 4096:
          for (int t = 0; t < 4; t++) mB[t] = {p, (size_t)t * H};
          break;
        case 6144:
          for (int t = 0; t < 6; t++) sB[t] = {p, (size_t)t * H};
          break;
        default: break;
      }
    }
  }

  // ---- workspace layout (ushort units) ----
  ushort_t* wsp = (ushort_t*)d_ws;
  size_t off = 0;
  int* flags = (int*)wsp; off += 32;
  ushort_t* xc = wsp + off; off += (size_t)Bm * DIN;
  __hip_bfloat16* r[5];
  for (int i = 0; i < 5; i++) { r[i] = (__hip_bfloat16*)(wsp + off); off += (size_t)Bm * H; }
  ushort_t* wWf = wsp + off; off += (size_t)H * DIN;
  ushort_t* wMain[4];
  for (int i = 0; i < 4; i++) { wMain[i] = wsp + off; off += HH; }
  ushort_t* wSkip[6];
  for (int k = 0; k < 6; k++) { wSkip[k] = wsp + off; off += HH; }
  ushort_t* wWo = wsp + off; off += (size_t)1024 * 1024;  // zero-padded to 1024 rows
  ushort_t* cbf_ = wsp + off; off += 1024;
  ushort_t* cmB[4];
  for (int i = 0; i < 4; i++) { cmB[i] = wsp + off; off += 1024; }
  ushort_t* csB[6];
  for (int k = 0; k < 6; k++) { csB[k] = wsp + off; off += 1024; }
  ushort_t* cbo = wsp + off; off += 1024;                 // tail 1000..1023 zeroed

  // ---- launches ----
  detect_kernel<<<1, 256, 0, stream>>>((const ushort_t*)x.p, (const ushort_t*)mf.p, flags);
  convert_x<<<(Bm * DIN) / (8 * 256), 256, 0, stream>>>(x.p, xc, flags, Bm * DIN);

  PrepAll p;
  p.e[0]  = { Wf.p, Wf.off, mf.p, mf.off, wWf, H * DIN, H * DIN };
  for (int i = 0; i < 4; i++)
    p.e[1 + i] = { mW[i].p, mW[i].off, mM[i].p, mM[i].off, wMain[i], (int)HH, (int)HH };
  for (int k = 0; k < 6; k++)
    p.e[5 + k] = { sW[k].p, sW[k].off, sM[k].p, sM[k].off, wSkip[k], (int)HH, (int)HH };
  p.e[11] = { Wo.p, Wo.off, mo.p, mo.off, wWo, 1024 * 1024, Cn * H };
  p.e[12] = { bf.p, bf.off, nullptr, 0, cbf_, H, H };
  for (int i = 0; i < 4; i++)
    p.e[13 + i] = { mB[i].p, mB[i].off, nullptr, 0, cmB[i], H, H };
  for (int k = 0; k < 6; k++)
    p.e[17 + k] = { sB[k].p, sB[k].off, nullptr, 0, csB[k], H, H };
  p.e[23] = { bo.p, bo.off, nullptr, 0, cbo, 1024, Cn };
  prep_weights<<<dim3(64, 24), dim3(256), 0, stream>>>(p, flags);

  const dim3 g(8, 64), b(256);

  GemmArgs a0; a0.s[0] = { xc, wWf, cbf_ };
  gemm_multi<1, true, false><<<g, b, 0, stream>>>(a0, r[0], nullptr, DIN, H, H);

  GemmArgs a1; a1.s[0] = { (ushort_t*)r[0], wMain[0], cmB[0] };
  gemm_multi<1, true, false><<<g, b, 0, stream>>>(a1, r[1], nullptr, H, H, H);

  GemmArgs a2;
  a2.s[0] = { (ushort_t*)r[1], wMain[1], cmB[1] };
  a2.s[1] = { (ushort_t*)r[0], wSkip[0], csB[0] };
  gemm_multi<2, true, false><<<g, b, 0, stream>>>(a2, r[2], nullptr, H, H, H);

  GemmArgs a3;
  a3.s[0] = { (ushort_t*)r[2], wMain[2], cmB[2] };
  a3.s[1] = { (ushort_t*)r[0], wSkip[1], csB[1] };
  a3.s[2] = { (ushort_t*)r[1], wSkip[2], csB[2] };
  gemm_multi<3, true, false><<<g, b, 0, stream>>>(a3, r[3], nullptr, H, H, H);

  GemmArgs a4;
  a4.s[0] = { (ushort_t*)r[3], wMain[3], cmB[3] };
  a4.s[1] = { (ushort_t*)r[0], wSkip[3], csB[3] };
  a4.s[2] = { (ushort_t*)r[1], wSkip[4], csB[4] };
  a4.s[3] = { (ushort_t*)r[2], wSkip[5], csB[5] };
  gemm_multi<4, true, false><<<g, b, 0, stream>>>(a4, r[4], nullptr, H, H, H);

  GemmArgs ao; ao.s[0] = { (ushort_t*)r[4], wWo, cbo };
  gemm_multi<1, false, true><<<g, b, 0, stream>>>(ao, d_out, flags, H, Cn, Cn);
}

// Round 5
// 606.995 us; speedup vs baseline: 1.2696x; 1.0950x over previous
//
#include <hip/hip_runtime.h>
#include <hip/hip_bf16.h>
#include <stdint.h>

// MaskedDeepDAN on MI355X (gfx950). B=8192, D_IN=2048, H=1024, C=1000.
// R5: gemm_multi is latency-bound at 2 blocks/CU (512-block grid is a hard
// cap at 128x128 tiles). Changes:
//  (1) explicit LDS double-buffer with flattened (source x k) staging stream:
//      prefetch tile k+1 (crossing source boundaries) immediately after the
//      barrier so the vmcnt(0) drain overlaps ds_read+16xMFMA of tile k.
//  (2) convert_x folded into prep_weights (one launch fewer, same pass).
//  (3) __launch_bounds__(256,2): 4-wave blocks, 2 blocks/CU, VGPR cap 256.
// Input resolution by size signature + on-device dtype detection (verified R3).

typedef unsigned short ushort_t;
typedef __bf16 bf16x8 __attribute__((ext_vector_type(8)));
typedef float f32x4 __attribute__((ext_vector_type(4)));

__device__ __forceinline__ void gl_lds16(const void* g, void* l) {
  typedef __attribute__((address_space(1))) void gvoid;
  typedef __attribute__((address_space(3))) void lvoid;
  __builtin_amdgcn_global_load_lds((gvoid*)(void*)g, (lvoid*)l, 16, 0, 0);
}

__device__ __forceinline__ ushort_t f2b(float f) {
  __hip_bfloat16 h = (__hip_bfloat16)f;
  return *(ushort_t*)&h;
}

// ---------------- dtype detection (verified R3) ----------------
// flags[0] = 1 if floats are fp32, 0 if bf16
// flags[1] = mask mode: 0=int32, 1=uint8, 2=bf16(u16), 3=fp32
__global__ void detect_kernel(const ushort_t* x, const ushort_t* mf, int* flags) {
  __shared__ int s[4];
  if (threadIdx.x < 4) s[threadIdx.x] = 0;
  __syncthreads();
  int expout = 0, m3f80_even = 0, m3f80_odd = 0, mhi01 = 0;
  for (int k = threadIdx.x; k < 2048; k += 256) {
    ushort_t w = x[k];
    int e = (w >> 7) & 0xFF;
    if (e < 96 || e > 144) expout++;
    ushort_t mw = mf[k];
    if (mw == 0x3F80) { if (k & 1) m3f80_odd++; else m3f80_even++; }
    if ((mw >> 8) == 1) mhi01++;
  }
  atomicAdd(&s[0], expout);
  atomicAdd(&s[1], m3f80_even);
  atomicAdd(&s[2], m3f80_odd);
  atomicAdd(&s[3], mhi01);
  __syncthreads();
  if (threadIdx.x == 0) {
    flags[0] = (s[0] > 100) ? 1 : 0;
    int mmode = 0;
    if (s[1] > 100) mmode = 2;
    else if (s[2] > 100) mmode = 3;
    else if (s[3] > 200) mmode = 1;
    flags[1] = mmode;
  }
}

// -------- masking + dtype conversion (weights, biases, and x) --------
// All n and valid are multiples of 8.
struct PrepEnt {
  const void* w; size_t woff;
  const void* m; size_t moff;   // nullptr -> no mask
  ushort_t* o;
  int n;
  int valid;                    // i >= valid -> 0
};
struct PrepAll { PrepEnt e[25]; };

__global__ void prep_weights(PrepAll p, const int* flags) {
  const bool f32 = flags[0] != 0;
  const int mmode = flags[1];
  const PrepEnt e = p.e[blockIdx.y];
  const int nch = e.n >> 3;
  const int stride = blockDim.x * gridDim.x;
  for (int ci = blockIdx.x * blockDim.x + threadIdx.x; ci < nch; ci += stride) {
    const int i = ci << 3;
    ushort_t o[8] = {0, 0, 0, 0, 0, 0, 0, 0};
    if (i < e.valid) {
      ushort_t wb[8];
      if (f32) {
        const float* wp = (const float*)e.w + e.woff + i;
        float4 a = *(const float4*)wp;
        float4 b = *(const float4*)(wp + 4);
        wb[0] = f2b(a.x); wb[1] = f2b(a.y); wb[2] = f2b(a.z); wb[3] = f2b(a.w);
        wb[4] = f2b(b.x); wb[5] = f2b(b.y); wb[6] = f2b(b.z); wb[7] = f2b(b.w);
      } else {
        *(uint4*)wb = *(const uint4*)((const ushort_t*)e.w + e.woff + i);
      }
      unsigned mk = 0xFF;
      if (e.m) {
        mk = 0;
        if (mmode == 0) {
          const int4* mp = (const int4*)((const int*)e.m + e.moff + i);
          int4 a = mp[0], b = mp[1];
          mk = (a.x != 0) | ((a.y != 0) << 1) | ((a.z != 0) << 2) | ((a.w != 0) << 3) |
               ((b.x != 0) << 4) | ((b.y != 0) << 5) | ((b.z != 0) << 6) | ((b.w != 0) << 7);
        } else if (mmode == 1) {
          const uint2 mv = *(const uint2*)((const unsigned char*)e.m + e.moff + i);
          const unsigned char* mb = (const unsigned char*)&mv;
          for (int j = 0; j < 8; j++) mk |= (mb[j] != 0) << j;
        } else if (mmode == 2) {
          uint4 mv = *(const uint4*)((const ushort_t*)e.m + e.moff + i);
          const ushort_t* ms = (const ushort_t*)&mv;
          for (int j = 0; j < 8; j++) mk |= (ms[j] != 0) << j;
        } else {
          const uint4* mp = (const uint4*)((const unsigned int*)e.m + e.moff + i);
          uint4 a = mp[0], b = mp[1];
          const unsigned* u = (const unsigned*)&a;
          const unsigned* v = (const unsigned*)&b;
          for (int j = 0; j < 4; j++) mk |= (u[j] != 0) << j;
          for (int j = 0; j < 4; j++) mk |= (v[j] != 0) << (4 + j);
        }
      }
#pragma unroll
      for (int j = 0; j < 8; j++) o[j] = ((mk >> j) & 1) ? wb[j] : (ushort_t)0;
    }
    *(uint4*)(e.o + i) = *(uint4*)o;
  }
}

// ---------------- fused multi-source GEMM, double-buffered ----------------
// C[M,N] = sum_s relu(A_s[M,K] * B_s[N,K]^T + bias_s)
// grid = (N_pad/128, M/128), block = 256 (4 waves, 2x2).
struct GemmSrc { const ushort_t* A; const ushort_t* B; const ushort_t* bias; };
struct GemmArgs { GemmSrc s[4]; };

template <int NSRC, bool RELU, bool NGUARD>
__launch_bounds__(256, 2)
__global__ void gemm_multi(GemmArgs args, void* Cv, const int* of32flag,
                           int K, int N_real, int ldc)
{
  __shared__ __align__(16) ushort_t As[2][128 * 32];
  __shared__ __align__(16) ushort_t Bs[2][128 * 32];

  const bool of32 = (of32flag != nullptr) && (of32flag[0] != 0);
  __hip_bfloat16* C = (__hip_bfloat16*)Cv;
  float* Cf = (float*)Cv;

  const int tid  = threadIdx.x;
  const int lane = tid & 63;
  const int wave = tid >> 6;
  const int wm = (wave >> 1) * 64;
  const int wn = (wave & 1) * 64;
  const int fr = lane & 15;
  const int kg = lane >> 4;
  const int bm = blockIdx.y * 128;
  const int bn = blockIdx.x * 128;

  const int srow = tid >> 2;
  const int scol = (tid & 3) * 8;
  const size_t aoff = (size_t)(bm + srow) * K + scol;
  const size_t boff = (size_t)(bn + srow) * K + scol;
  const size_t rowskip = (size_t)64 * K;

  // stage one 128x32 A-tile + B-tile into buffer `buf`
  auto stage = [&](const ushort_t* gA, const ushort_t* gB, int buf) {
    ushort_t* lA = &As[buf][wave * 512];
    ushort_t* lB = &Bs[buf][wave * 512];
    gl_lds16(gA, lA);
    gl_lds16(gA + rowskip, lA + 2048);
    gl_lds16(gB, lB);
    gl_lds16(gB + rowskip, lB + 2048);
  };

  f32x4 acc[4][4], out_acc[4][4];
#pragma unroll
  for (int i = 0; i < 4; i++)
#pragma unroll
    for (int j = 0; j < 4; j++) {
      acc[i][j] = (f32x4){0.f, 0.f, 0.f, 0.f};
      out_acc[i][j] = (f32x4){0.f, 0.f, 0.f, 0.f};
    }

  // initial tile: source 0, k=0 -> buf 0
  stage(args.s[0].A + aoff, args.s[0].B + boff, 0);
  int cur = 0;

#pragma unroll
  for (int s = 0; s < NSRC; ++s) {
    const ushort_t* gA = args.s[s].A + aoff;
    const ushort_t* gB = args.s[s].B + boff;
    for (int k0 = 0; k0 < K; k0 += 32) {
      __syncthreads();   // drains vmcnt (tile `cur` staged) + lgkm (prev ds_reads)
      // prefetch next tile (possibly next source) into the other buffer
      if (k0 + 32 < K) {
        stage(gA + k0 + 32, gB + k0 + 32, cur ^ 1);
      } else if (s + 1 < NSRC) {
        stage(args.s[s + 1].A + aoff, args.s[s + 1].B + boff, cur ^ 1);
      }

      const bf16x8* Asv = (const bf16x8*)As[cur];
      const bf16x8* Bsv = (const bf16x8*)Bs[cur];
      bf16x8 af[4], bfr[4];
#pragma unroll
      for (int i = 0; i < 4; i++) af[i]  = Asv[(wm + i * 16 + fr) * 4 + kg];
#pragma unroll
      for (int i = 0; i < 4; i++) bfr[i] = Bsv[(wn + i * 16 + fr) * 4 + kg];
#pragma unroll
      for (int mi = 0; mi < 4; mi++)
#pragma unroll
        for (int ni = 0; ni < 4; ni++)
          acc[mi][ni] = __builtin_amdgcn_mfma_f32_16x16x32_bf16(
              af[mi], bfr[ni], acc[mi][ni], 0, 0, 0);
      cur ^= 1;
    }

    // per-source fold (bias + relu -> fp32 out_acc); overlaps next source's
    // in-flight prefetch. Skipped for NSRC==1 (folded into the store).
    if (NSRC > 1) {
      const ushort_t* bias = args.s[s].bias;
#pragma unroll
      for (int ni = 0; ni < 4; ni++) {
        const int c = bn + wn + ni * 16 + fr;
        const float bb = (float)*(const __hip_bfloat16*)(bias + c);
#pragma unroll
        for (int mi = 0; mi < 4; mi++)
#pragma unroll
          for (int j = 0; j < 4; j++) {
            float v = acc[mi][ni][j] + bb;
            if (RELU) v = fmaxf(v, 0.0f);
            out_acc[mi][ni][j] += v;
            acc[mi][ni][j] = 0.0f;
          }
      }
    }
  }

  // store: C/D layout col = lane&15, row = (lane>>4)*4 + reg
#pragma unroll
  for (int ni = 0; ni < 4; ni++) {
    const int c = bn + wn + ni * 16 + fr;
    if (NGUARD && c >= N_real) continue;
    float bb = 0.0f;
    if (NSRC == 1) bb = (float)*(const __hip_bfloat16*)(args.s[0].bias + c);
#pragma unroll
    for (int mi = 0; mi < 4; mi++) {
      const int r0 = bm + wm + mi * 16 + kg * 4;
#pragma unroll
      for (int j = 0; j < 4; j++) {
        const size_t idx = (size_t)(r0 + j) * ldc + c;
        float v;
        if (NSRC == 1) {
          v = acc[mi][ni][j] + bb;
          if (RELU) v = fmaxf(v, 0.0f);
        } else {
          v = out_acc[mi][ni][j];
        }
        if (of32) Cf[idx] = v;
        else      C[idx]  = (__hip_bfloat16)v;
      }
    }
  }
}

extern "C" void kernel_launch(void* const* d_in, const int* in_sizes, int n_in,
                              void* d_out, int out_size, void* d_ws, size_t ws_size,
                              hipStream_t stream) {
  (void)out_size; (void)ws_size;
  const int Bm = 8192, DIN = 2048, H = 1024, Cn = 1000;
  const size_t HH = (size_t)H * H;

  // ---- size-signature input resolver (verified R3) ----
  struct PO { const void* p; size_t off; };
  PO x{d_in[0], 0}, Wf{d_in[0], 0}, mf{d_in[0], 0}, Wo{d_in[0], 0}, mo{d_in[0], 0};
  PO bf{d_in[0], 0}, bo{d_in[0], 0};
  PO mW[4], mM[4], mB[4], sW[6], sM[6], sB[6];
  for (int i = 0; i < 4; i++) { mW[i] = {d_in[0], 0}; mM[i] = mW[i]; mB[i] = mW[i]; }
  for (int i = 0; i < 6; i++) { sW[i] = {d_in[0], 0}; sM[i] = sW[i]; sB[i] = sW[i]; }

  {
    int c2M = 0, c1M = 0, c1k = 0, cWoMo = 0, c4 = 0, c6 = 0;
    for (int i = 0; i < n_in; i++) {
      const int s = in_sizes[i];
      const void* p = d_in[i];
      switch (s) {
        case 16777216: x = {p, 0}; break;
        case 2097152:  if (c2M++ == 0) Wf = {p, 0}; else mf = {p, 0}; break;
        case 1048576: {
          int j = c1M++;
          if (j < 4)       mW[j]      = {p, 0};
          else if (j < 8)  mM[j - 4]  = {p, 0};
          else if (j < 14) sW[j - 8]  = {p, 0};
          else if (j < 20) sM[j - 14] = {p, 0};
          break;
        }
        case 1024: {
          int j = c1k++;
          if (j == 0)      bf        = {p, 0};
          else if (j < 5)  mB[j - 1] = {p, 0};
          else if (j < 11) sB[j - 5] = {p, 0};
          break;
        }
        case 1024000: if (cWoMo++ == 0) Wo = {p, 0}; else mo = {p, 0}; break;
        case 1000: bo = {p, 0}; break;
        case 4194304:
          for (int t = 0; t < 4; t++) {
            if (c4 == 0) mW[t] = {p, t * HH}; else mM[t] = {p, t * HH};
          }
          c4++; break;
        case 6291456:
          for (int t = 0; t < 6; t++) {
            if (c6 == 0) sW[t] = {p, t * HH}; else sM[t] = {p, t * HH};
          }
          c6++; break;
        case 4096:
          for (int t = 0; t < 4; t++) mB[t] = {p, (size_t)t * H};
          break;
        case 6144:
          for (int t = 0; t < 6; t++) sB[t] = {p, (size_t)t * H};
          break;
        default: break;
      }
    }
  }

  // ---- workspace layout (ushort units) ----
  ushort_t* wsp = (ushort_t*)d_ws;
  size_t off = 0;
  int* flags = (int*)wsp; off += 32;
  ushort_t* xc = wsp + off; off += (size_t)Bm * DIN;
  __hip_bfloat16* r[5];
  for (int i = 0; i < 5; i++) { r[i] = (__hip_bfloat16*)(wsp + off); off += (size_t)Bm * H; }
  ushort_t* wWf = wsp + off; off += (size_t)H * DIN;
  ushort_t* wMain[4];
  for (int i = 0; i < 4; i++) { wMain[i] = wsp + off; off += HH; }
  ushort_t* wSkip[6];
  for (int k = 0; k < 6; k++) { wSkip[k] = wsp + off; off += HH; }
  ushort_t* wWo = wsp + off; off += (size_t)1024 * 1024;  // zero-padded to 1024 rows
  ushort_t* cbf_ = wsp + off; off += 1024;
  ushort_t* cmB[4];
  for (int i = 0; i < 4; i++) { cmB[i] = wsp + off; off += 1024; }
  ushort_t* csB[6];
  for (int k = 0; k < 6; k++) { csB[k] = wsp + off; off += 1024; }
  ushort_t* cbo = wsp + off; off += 1024;                 // tail 1000..1023 zeroed

  // ---- launches ----
  detect_kernel<<<1, 256, 0, stream>>>((const ushort_t*)x.p, (const ushort_t*)mf.p, flags);

  PrepAll p;
  p.e[0]  = { Wf.p, Wf.off, mf.p, mf.off, wWf, H * DIN, H * DIN };
  for (int i = 0; i < 4; i++)
    p.e[1 + i] = { mW[i].p, mW[i].off, mM[i].p, mM[i].off, wMain[i], (int)HH, (int)HH };
  for (int k = 0; k < 6; k++)
    p.e[5 + k] = { sW[k].p, sW[k].off, sM[k].p, sM[k].off, wSkip[k], (int)HH, (int)HH };
  p.e[11] = { Wo.p, Wo.off, mo.p, mo.off, wWo, 1024 * 1024, Cn * H };
  p.e[12] = { bf.p, bf.off, nullptr, 0, cbf_, H, H };
  for (int i = 0; i < 4; i++)
    p.e[13 + i] = { mB[i].p, mB[i].off, nullptr, 0, cmB[i], H, H };
  for (int k = 0; k < 6; k++)
    p.e[17 + k] = { sB[k].p, sB[k].off, nullptr, 0, csB[k], H, H };
  p.e[23] = { bo.p, bo.off, nullptr, 0, cbo, 1024, Cn };
  p.e[24] = { x.p, x.off, nullptr, 0, xc, Bm * DIN, Bm * DIN };   // x conversion
  prep_weights<<<dim3(256, 25), dim3(256), 0, stream>>>(p, flags);

  const dim3 g(8, 64), b(256);

  GemmArgs a0; a0.s[0] = { xc, wWf, cbf_ };
  gemm_multi<1, true, false><<<g, b, 0, stream>>>(a0, r[0], nullptr, DIN, H, H);

  GemmArgs a1; a1.s[0] = { (ushort_t*)r[0], wMain[0], cmB[0] };
  gemm_multi<1, true, false><<<g, b, 0, stream>>>(a1, r[1], nullptr, H, H, H);

  GemmArgs a2;
  a2.s[0] = { (ushort_t*)r[1], wMain[1], cmB[1] };
  a2.s[1] = { (ushort_t*)r[0], wSkip[0], csB[0] };
  gemm_multi<2, true, false><<<g, b, 0, stream>>>(a2, r[2], nullptr, H, H, H);

  GemmArgs a3;
  a3.s[0] = { (ushort_t*)r[2], wMain[2], cmB[2] };
  a3.s[1] = { (ushort_t*)r[0], wSkip[1], csB[1] };
  a3.s[2] = { (ushort_t*)r[1], wSkip[2], csB[2] };
  gemm_multi<3, true, false><<<g, b, 0, stream>>>(a3, r[3], nullptr, H, H, H);

  GemmArgs a4;
  a4.s[0] = { (ushort_t*)r[3], wMain[3], cmB[3] };
  a4.s[1] = { (ushort_t*)r[0], wSkip[3], csB[3] };
  a4.s[2] = { (ushort_t*)r[1], wSkip[4], csB[4] };
  a4.s[3] = { (ushort_t*)r[2], wSkip[5], csB[5] };
  gemm_multi<4, true, false><<<g, b, 0, stream>>>(a4, r[4], nullptr, H, H, H);

  GemmArgs ao; ao.s[0] = { (ushort_t*)r[4], wWo, cbo };
  gemm_multi<1, false, true><<<g, b, 0, stream>>>(ao, d_out, flags, H, Cn, Cn);
}

// Round 6
// 555.509 us; speedup vs baseline: 1.3873x; 1.0927x over previous
//
#include <hip/hip_runtime.h>
#include <hip/hip_bf16.h>
#include <stdint.h>

// MaskedDeepDAN on MI355X (gfx950). B=8192, D_IN=2048, H=1024, C=1000.
// R6: attack the two counter findings from R5 (FETCH 297MB vs ~90MB ideal;
// SQ_LDS_BANK_CONFLICT 8.4M cyc):
//  (1) XCD-aware tile remap: all 8 N-tiles sharing an A-row-block land on the
//      same XCD (round-robin lid%8 assumption; robust to contiguous too).
//  (2) XOR chunk swizzle in LDS: staging permutes the GLOBAL k-chunk per lane
//      (LDS dest stays lane-contiguous, global 64B lines still fully
//      coalesced); fragment reads use sw = kg ^ ((fr>>1)&3) -> 2-way max
//      bank aliasing (free) instead of 8-way.
// Carried: per-layer fused multi-source GEMM, LDS double-buffer, fused
// bias+relu in fp32 regs, prep/detect pipeline (verified R3-R5).

typedef unsigned short ushort_t;
typedef __bf16 bf16x8 __attribute__((ext_vector_type(8)));
typedef float f32x4 __attribute__((ext_vector_type(4)));

__device__ __forceinline__ void gl_lds16(const void* g, void* l) {
  typedef __attribute__((address_space(1))) void gvoid;
  typedef __attribute__((address_space(3))) void lvoid;
  __builtin_amdgcn_global_load_lds((gvoid*)(void*)g, (lvoid*)l, 16, 0, 0);
}

__device__ __forceinline__ ushort_t f2b(float f) {
  __hip_bfloat16 h = (__hip_bfloat16)f;
  return *(ushort_t*)&h;
}

// ---------------- dtype detection (verified R3) ----------------
// flags[0] = 1 if floats are fp32, 0 if bf16
// flags[1] = mask mode: 0=int32, 1=uint8, 2=bf16(u16), 3=fp32
__global__ void detect_kernel(const ushort_t* x, const ushort_t* mf, int* flags) {
  __shared__ int s[4];
  if (threadIdx.x < 4) s[threadIdx.x] = 0;
  __syncthreads();
  int expout = 0, m3f80_even = 0, m3f80_odd = 0, mhi01 = 0;
  for (int k = threadIdx.x; k < 2048; k += 256) {
    ushort_t w = x[k];
    int e = (w >> 7) & 0xFF;
    if (e < 96 || e > 144) expout++;
    ushort_t mw = mf[k];
    if (mw == 0x3F80) { if (k & 1) m3f80_odd++; else m3f80_even++; }
    if ((mw >> 8) == 1) mhi01++;
  }
  atomicAdd(&s[0], expout);
  atomicAdd(&s[1], m3f80_even);
  atomicAdd(&s[2], m3f80_odd);
  atomicAdd(&s[3], mhi01);
  __syncthreads();
  if (threadIdx.x == 0) {
    flags[0] = (s[0] > 100) ? 1 : 0;
    int mmode = 0;
    if (s[1] > 100) mmode = 2;
    else if (s[2] > 100) mmode = 3;
    else if (s[3] > 200) mmode = 1;
    flags[1] = mmode;
  }
}

// -------- masking + dtype conversion (weights, biases, and x) --------
struct PrepEnt {
  const void* w; size_t woff;
  const void* m; size_t moff;   // nullptr -> no mask
  ushort_t* o;
  int n;
  int valid;                    // i >= valid -> 0
};
struct PrepAll { PrepEnt e[25]; };

__global__ void prep_weights(PrepAll p, const int* flags) {
  const bool f32 = flags[0] != 0;
  const int mmode = flags[1];
  const PrepEnt e = p.e[blockIdx.y];
  const int nch = e.n >> 3;
  const int stride = blockDim.x * gridDim.x;
  for (int ci = blockIdx.x * blockDim.x + threadIdx.x; ci < nch; ci += stride) {
    const int i = ci << 3;
    ushort_t o[8] = {0, 0, 0, 0, 0, 0, 0, 0};
    if (i < e.valid) {
      ushort_t wb[8];
      if (f32) {
        const float* wp = (const float*)e.w + e.woff + i;
        float4 a = *(const float4*)wp;
        float4 b = *(const float4*)(wp + 4);
        wb[0] = f2b(a.x); wb[1] = f2b(a.y); wb[2] = f2b(a.z); wb[3] = f2b(a.w);
        wb[4] = f2b(b.x); wb[5] = f2b(b.y); wb[6] = f2b(b.z); wb[7] = f2b(b.w);
      } else {
        *(uint4*)wb = *(const uint4*)((const ushort_t*)e.w + e.woff + i);
      }
      unsigned mk = 0xFF;
      if (e.m) {
        mk = 0;
        if (mmode == 0) {
          const int4* mp = (const int4*)((const int*)e.m + e.moff + i);
          int4 a = mp[0], b = mp[1];
          mk = (a.x != 0) | ((a.y != 0) << 1) | ((a.z != 0) << 2) | ((a.w != 0) << 3) |
               ((b.x != 0) << 4) | ((b.y != 0) << 5) | ((b.z != 0) << 6) | ((b.w != 0) << 7);
        } else if (mmode == 1) {
          const uint2 mv = *(const uint2*)((const unsigned char*)e.m + e.moff + i);
          const unsigned char* mb = (const unsigned char*)&mv;
          for (int j = 0; j < 8; j++) mk |= (mb[j] != 0) << j;
        } else if (mmode == 2) {
          uint4 mv = *(const uint4*)((const ushort_t*)e.m + e.moff + i);
          const ushort_t* ms = (const ushort_t*)&mv;
          for (int j = 0; j < 8; j++) mk |= (ms[j] != 0) << j;
        } else {
          const uint4* mp = (const uint4*)((const unsigned int*)e.m + e.moff + i);
          uint4 a = mp[0], b = mp[1];
          const unsigned* u = (const unsigned*)&a;
          const unsigned* v = (const unsigned*)&b;
          for (int j = 0; j < 4; j++) mk |= (u[j] != 0) << j;
          for (int j = 0; j < 4; j++) mk |= (v[j] != 0) << (4 + j);
        }
      }
#pragma unroll
      for (int j = 0; j < 8; j++) o[j] = ((mk >> j) & 1) ? wb[j] : (ushort_t)0;
    }
    *(uint4*)(e.o + i) = *(uint4*)o;
  }
}

// ---------------- fused multi-source GEMM, double-buffered ----------------
// C[M,N] = sum_s relu(A_s[M,K] * B_s[N,K]^T + bias_s)
// grid = (8, 64) fixed (N_pad=1024 -> 8 tiles, M=8192 -> 64 tiles), block 256.
struct GemmSrc { const ushort_t* A; const ushort_t* B; const ushort_t* bias; };
struct GemmArgs { GemmSrc s[4]; };

template <int NSRC, bool RELU, bool NGUARD>
__launch_bounds__(256, 2)
__global__ void gemm_multi(GemmArgs args, void* Cv, const int* of32flag,
                           int K, int N_real, int ldc)
{
  __shared__ __align__(16) ushort_t As[2][128 * 32];
  __shared__ __align__(16) ushort_t Bs[2][128 * 32];

  const bool of32 = (of32flag != nullptr) && (of32flag[0] != 0);
  __hip_bfloat16* C = (__hip_bfloat16*)Cv;
  float* Cf = (float*)Cv;

  const int tid  = threadIdx.x;
  const int lane = tid & 63;
  const int wave = tid >> 6;
  const int wm = (wave >> 1) * 64;
  const int wn = (wave & 1) * 64;
  const int fr = lane & 15;
  const int kg = lane >> 4;

  // XCD-aware remap: lid%8 = XCD (round-robin assumption). Each XCD gets
  // 8 M-tiles x all 8 N-tiles; the 8 blocks sharing one A-row-block are
  // consecutive on the SAME XCD -> A fetched once per XCD L2, not 8x.
  const int lid = blockIdx.y * 8 + blockIdx.x;      // gridDim.x == 8
  const int s8  = lid >> 3;
  const int bm  = ((lid & 7) * 8 + (s8 >> 3)) * 128;
  const int bn  = (s8 & 7) * 128;

  // staging: thread t covers row t/4; global k-chunk XOR-permuted so that
  // fragment reads are 2-way-bank-aliased (free). LDS dest stays t*16.
  const int srow = tid >> 2;
  const int scol = (((tid & 3) ^ ((srow >> 1) & 3)) * 8);
  const size_t aoff = (size_t)(bm + srow) * K + scol;
  const size_t boff = (size_t)(bn + srow) * K + scol;
  const size_t rowskip = (size_t)64 * K;

  auto stage = [&](const ushort_t* gA, const ushort_t* gB, int buf) {
    ushort_t* lA = &As[buf][wave * 512];
    ushort_t* lB = &Bs[buf][wave * 512];
    gl_lds16(gA, lA);
    gl_lds16(gA + rowskip, lA + 2048);
    gl_lds16(gB, lB);
    gl_lds16(gB + rowskip, lB + 2048);
  };

  f32x4 acc[4][4], out_acc[4][4];
#pragma unroll
  for (int i = 0; i < 4; i++)
#pragma unroll
    for (int j = 0; j < 4; j++) {
      acc[i][j] = (f32x4){0.f, 0.f, 0.f, 0.f};
      out_acc[i][j] = (f32x4){0.f, 0.f, 0.f, 0.f};
    }

  stage(args.s[0].A + aoff, args.s[0].B + boff, 0);
  int cur = 0;

  // fragment-read chunk swizzle: row>>1 & 3 == fr>>1 & 3 (wm, i*16 are 0 mod 4
  // after >>1), so the XOR index is constant per lane.
  const int sw = kg ^ ((fr >> 1) & 3);

#pragma unroll
  for (int s = 0; s < NSRC; ++s) {
    const ushort_t* gA = args.s[s].A + aoff;
    const ushort_t* gB = args.s[s].B + boff;
    for (int k0 = 0; k0 < K; k0 += 32) {
      __syncthreads();   // drains vmcnt (tile `cur` staged) + lgkm (prev ds_reads)
      if (k0 + 32 < K) {
        stage(gA + k0 + 32, gB + k0 + 32, cur ^ 1);
      } else if (s + 1 < NSRC) {
        stage(args.s[s + 1].A + aoff, args.s[s + 1].B + boff, cur ^ 1);
      }

      const bf16x8* Asv = (const bf16x8*)As[cur];
      const bf16x8* Bsv = (const bf16x8*)Bs[cur];
      bf16x8 af[4], bfr[4];
#pragma unroll
      for (int i = 0; i < 4; i++) af[i]  = Asv[(wm + i * 16 + fr) * 4 + sw];
#pragma unroll
      for (int i = 0; i < 4; i++) bfr[i] = Bsv[(wn + i * 16 + fr) * 4 + sw];
#pragma unroll
      for (int mi = 0; mi < 4; mi++)
#pragma unroll
        for (int ni = 0; ni < 4; ni++)
          acc[mi][ni] = __builtin_amdgcn_mfma_f32_16x16x32_bf16(
              af[mi], bfr[ni], acc[mi][ni], 0, 0, 0);
      cur ^= 1;
    }

    if (NSRC > 1) {
      const ushort_t* bias = args.s[s].bias;
#pragma unroll
      for (int ni = 0; ni < 4; ni++) {
        const int c = bn + wn + ni * 16 + fr;
        const float bb = (float)*(const __hip_bfloat16*)(bias + c);
#pragma unroll
        for (int mi = 0; mi < 4; mi++)
#pragma unroll
          for (int j = 0; j < 4; j++) {
            float v = acc[mi][ni][j] + bb;
            if (RELU) v = fmaxf(v, 0.0f);
            out_acc[mi][ni][j] += v;
            acc[mi][ni][j] = 0.0f;
          }
      }
    }
  }

  // store: C/D layout col = lane&15, row = (lane>>4)*4 + reg
#pragma unroll
  for (int ni = 0; ni < 4; ni++) {
    const int c = bn + wn + ni * 16 + fr;
    if (NGUARD && c >= N_real) continue;
    float bb = 0.0f;
    if (NSRC == 1) bb = (float)*(const __hip_bfloat16*)(args.s[0].bias + c);
#pragma unroll
    for (int mi = 0; mi < 4; mi++) {
      const int r0 = bm + wm + mi * 16 + kg * 4;
#pragma unroll
      for (int j = 0; j < 4; j++) {
        const size_t idx = (size_t)(r0 + j) * ldc + c;
        float v;
        if (NSRC == 1) {
          v = acc[mi][ni][j] + bb;
          if (RELU) v = fmaxf(v, 0.0f);
        } else {
          v = out_acc[mi][ni][j];
        }
        if (of32) Cf[idx] = v;
        else      C[idx]  = (__hip_bfloat16)v;
      }
    }
  }
}

extern "C" void kernel_launch(void* const* d_in, const int* in_sizes, int n_in,
                              void* d_out, int out_size, void* d_ws, size_t ws_size,
                              hipStream_t stream) {
  (void)out_size; (void)ws_size;
  const int Bm = 8192, DIN = 2048, H = 1024, Cn = 1000;
  const size_t HH = (size_t)H * H;

  // ---- size-signature input resolver (verified R3) ----
  struct PO { const void* p; size_t off; };
  PO x{d_in[0], 0}, Wf{d_in[0], 0}, mf{d_in[0], 0}, Wo{d_in[0], 0}, mo{d_in[0], 0};
  PO bf{d_in[0], 0}, bo{d_in[0], 0};
  PO mW[4], mM[4], mB[4], sW[6], sM[6], sB[6];
  for (int i = 0; i < 4; i++) { mW[i] = {d_in[0], 0}; mM[i] = mW[i]; mB[i] = mW[i]; }
  for (int i = 0; i < 6; i++) { sW[i] = {d_in[0], 0}; sM[i] = sW[i]; sB[i] = sW[i]; }

  {
    int c2M = 0, c1M = 0, c1k = 0, cWoMo = 0, c4 = 0, c6 = 0;
    for (int i = 0; i < n_in; i++) {
      const int s = in_sizes[i];
      const void* p = d_in[i];
      switch (s) {
        case 16777216: x = {p, 0}; break;
        case 2097152:  if (c2M++ == 0) Wf = {p, 0}; else mf = {p, 0}; break;
        case 1048576: {
          int j = c1M++;
          if (j < 4)       mW[j]      = {p, 0};
          else if (j < 8)  mM[j - 4]  = {p, 0};
          else if (j < 14) sW[j - 8]  = {p, 0};
          else if (j < 20) sM[j - 14] = {p, 0};
          break;
        }
        case 1024: {
          int j = c1k++;
          if (j == 0)      bf        = {p, 0};
          else if (j < 5)  mB[j - 1] = {p, 0};
          else if (j < 11) sB[j - 5] = {p, 0};
          break;
        }
        case 1024000: if (cWoMo++ == 0) Wo = {p, 0}; else mo = {p, 0}; break;
        case 1000: bo = {p, 0}; break;
        case 4194304:
          for (int t = 0; t < 4; t++) {
            if (c4 == 0) mW[t] = {p, t * HH}; else mM[t] = {p, t * HH};
          }
          c4++; break;
        case 6291456:
          for (int t = 0; t < 6; t++) {
            if (c6 == 0) sW[t] = {p, t * HH}; else sM[t] = {p, t * HH};
          }
          c6++; break;
        case 4096:
          for (int t = 0; t < 4; t++) mB[t] = {p, (size_t)t * H};
          break;
        case 6144:
          for (int t = 0; t < 6; t++) sB[t] = {p, (size_t)t * H};
          break;
        default: break;
      }
    }
  }

  // ---- workspace layout (ushort units) ----
  ushort_t* wsp = (ushort_t*)d_ws;
  size_t off = 0;
  int* flags = (int*)wsp; off += 32;
  ushort_t* xc = wsp + off; off += (size_t)Bm * DIN;
  __hip_bfloat16* r[5];
  for (int i = 0; i < 5; i++) { r[i] = (__hip_bfloat16*)(wsp + off); off += (size_t)Bm * H; }
  ushort_t* wWf = wsp + off; off += (size_t)H * DIN;
  ushort_t* wMain[4];
  for (int i = 0; i < 4; i++) { wMain[i] = wsp + off; off += HH; }
  ushort_t* wSkip[6];
  for (int k = 0; k < 6; k++) { wSkip[k] = wsp + off; off += HH; }
  ushort_t* wWo = wsp + off; off += (size_t)1024 * 1024;  // zero-padded to 1024 rows
  ushort_t* cbf_ = wsp + off; off += 1024;
  ushort_t* cmB[4];
  for (int i = 0; i < 4; i++) { cmB[i] = wsp + off; off += 1024; }
  ushort_t* csB[6];
  for (int k = 0; k < 6; k++) { csB[k] = wsp + off; off += 1024; }
  ushort_t* cbo = wsp + off; off += 1024;                 // tail 1000..1023 zeroed

  // ---- launches ----
  detect_kernel<<<1, 256, 0, stream>>>((const ushort_t*)x.p, (const ushort_t*)mf.p, flags);

  PrepAll p;
  p.e[0]  = { Wf.p, Wf.off, mf.p, mf.off, wWf, H * DIN, H * DIN };
  for (int i = 0; i < 4; i++)
    p.e[1 + i] = { mW[i].p, mW[i].off, mM[i].p, mM[i].off, wMain[i], (int)HH, (int)HH };
  for (int k = 0; k < 6; k++)
    p.e[5 + k] = { sW[k].p, sW[k].off, sM[k].p, sM[k].off, wSkip[k], (int)HH, (int)HH };
  p.e[11] = { Wo.p, Wo.off, mo.p, mo.off, wWo, 1024 * 1024, Cn * H };
  p.e[12] = { bf.p, bf.off, nullptr, 0, cbf_, H, H };
  for (int i = 0; i < 4; i++)
    p.e[13 + i] = { mB[i].p, mB[i].off, nullptr, 0, cmB[i], H, H };
  for (int k = 0; k < 6; k++)
    p.e[17 + k] = { sB[k].p, sB[k].off, nullptr, 0, csB[k], H, H };
  p.e[23] = { bo.p, bo.off, nullptr, 0, cbo, 1024, Cn };
  p.e[24] = { x.p, x.off, nullptr, 0, xc, Bm * DIN, Bm * DIN };   // x conversion
  prep_weights<<<dim3(256, 25), dim3(256), 0, stream>>>(p, flags);

  const dim3 g(8, 64), b(256);

  GemmArgs a0; a0.s[0] = { xc, wWf, cbf_ };
  gemm_multi<1, true, false><<<g, b, 0, stream>>>(a0, r[0], nullptr, DIN, H, H);

  GemmArgs a1; a1.s[0] = { (ushort_t*)r[0], wMain[0], cmB[0] };
  gemm_multi<1, true, false><<<g, b, 0, stream>>>(a1, r[1], nullptr, H, H, H);

  GemmArgs a2;
  a2.s[0] = { (ushort_t*)r[1], wMain[1], cmB[1] };
  a2.s[1] = { (ushort_t*)r[0], wSkip[0], csB[0] };
  gemm_multi<2, true, false><<<g, b, 0, stream>>>(a2, r[2], nullptr, H, H, H);

  GemmArgs a3;
  a3.s[0] = { (ushort_t*)r[2], wMain[2], cmB[2] };
  a3.s[1] = { (ushort_t*)r[0], wSkip[1], csB[1] };
  a3.s[2] = { (ushort_t*)r[1], wSkip[2], csB[2] };
  gemm_multi<3, true, false><<<g, b, 0, stream>>>(a3, r[3], nullptr, H, H, H);

  GemmArgs a4;
  a4.s[0] = { (ushort_t*)r[3], wMain[3], cmB[3] };
  a4.s[1] = { (ushort_t*)r[0], wSkip[3], csB[3] };
  a4.s[2] = { (ushort_t*)r[1], wSkip[4], csB[4] };
  a4.s[3] = { (ushort_t*)r[2], wSkip[5], csB[5] };
  gemm_multi<4, true, false><<<g, b, 0, stream>>>(a4, r[4], nullptr, H, H, H);

  GemmArgs ao; ao.s[0] = { (ushort_t*)r[4], wWo, cbo };
  gemm_multi<1, false, true><<<g, b, 0, stream>>>(ao, d_out, flags, H, Cn, Cn);
}